// Round 2
// baseline (375.195 us; speedup 1.0000x reference)
//
#include <hip/hip_runtime.h>
#include <hip/hip_bf16.h>

typedef __attribute__((ext_vector_type(8))) short short8;
typedef __attribute__((ext_vector_type(4))) float floatx4;

#define T_SEQ 2048
#define NH    16
#define HD    64

__device__ __forceinline__ ushort f2bf(float f) {
    union { float f; unsigned u; } un; un.f = f;
    unsigned r = un.u + 0x7fff + ((un.u >> 16) & 1);
    return (ushort)(r >> 16);
}

// -------- transpose + convert: in fp32 [R][C] -> out bf16 [C][R] ----------
__global__ void transpose_f32_bf16(const float* __restrict__ in, ushort* __restrict__ out,
                                   int R, int C) {
    __shared__ ushort tile[32][33];
    const int tx = threadIdx.x & 31, ty = threadIdx.x >> 5;
    const int bx = blockIdx.x * 32;   // col base (in)
    const int by = blockIdx.y * 32;   // row base (in)
    #pragma unroll
    for (int i = ty; i < 32; i += 8)
        tile[i][tx] = f2bf(in[(size_t)(by + i) * C + bx + tx]);
    __syncthreads();
    #pragma unroll
    for (int i = ty; i < 32; i += 8)
        out[(size_t)(bx + i) * R + by + tx] = tile[tx][i];
}

// ---------------- GEMM: C[M][N] = A[M][K] * Bt[N][K]^T  (bf16 MFMA, fp32 acc) --
// EPI==0: A is fp32 (converted during staging); scatter bf16 into
//         q[B,H,T,hd], k[B,H,T,hd], vT[B,H,hd,T]  (N must be 3072)
// EPI==1: A is bf16; output fp32 row-major [M][N] into O0
template <int EPI>
__global__ __launch_bounds__(256, 2)
void gemm_bt(const void* __restrict__ Avoid, const ushort* __restrict__ Bt,
             void* __restrict__ O0, ushort* __restrict__ O1, ushort* __restrict__ O2,
             int M, int N, int K) {
    __shared__ __align__(16) ushort As[128 * 40];
    __shared__ __align__(16) ushort Bs[128 * 40];
    const int tid  = threadIdx.x;
    const int wave = tid >> 6, lane = tid & 63;
    const int quad = lane >> 4, l16 = lane & 15;
    const int wm = (wave >> 1) * 64, wn = (wave & 1) * 64;
    const int m0 = blockIdx.x * 128, n0 = blockIdx.y * 128;

    floatx4 acc[4][4];
    #pragma unroll
    for (int i = 0; i < 4; i++)
        #pragma unroll
        for (int j = 0; j < 4; j++)
            acc[i][j] = (floatx4){0.f, 0.f, 0.f, 0.f};

    for (int k0 = 0; k0 < K; k0 += 32) {
        __syncthreads();
        #pragma unroll
        for (int i = 0; i < 2; i++) {
            int c = tid + i * 256;          // 512 chunks of 8 bf16
            int row = c >> 2, col = (c & 3) * 8;
            if (EPI == 0) {
                const float* src = (const float*)Avoid + (size_t)(m0 + row) * K + k0 + col;
                float4 f0 = *(const float4*)(src);
                float4 f1 = *(const float4*)(src + 4);
                short8 v;
                v[0] = (short)f2bf(f0.x); v[1] = (short)f2bf(f0.y);
                v[2] = (short)f2bf(f0.z); v[3] = (short)f2bf(f0.w);
                v[4] = (short)f2bf(f1.x); v[5] = (short)f2bf(f1.y);
                v[6] = (short)f2bf(f1.z); v[7] = (short)f2bf(f1.w);
                *(short8*)(&As[row * 40 + col]) = v;
            } else {
                uint4 va = *(const uint4*)((const ushort*)Avoid + (size_t)(m0 + row) * K + k0 + col);
                *(uint4*)(&As[row * 40 + col]) = va;
            }
            uint4 vb = *(const uint4*)(Bt + (size_t)(n0 + row) * K + k0 + col);
            *(uint4*)(&Bs[row * 40 + col]) = vb;
        }
        __syncthreads();
        short8 af[4], bf[4];
        #pragma unroll
        for (int i = 0; i < 4; i++)
            af[i] = *(const short8*)(&As[(wm + i * 16 + l16) * 40 + quad * 8]);
        #pragma unroll
        for (int j = 0; j < 4; j++)
            bf[j] = *(const short8*)(&Bs[(wn + j * 16 + l16) * 40 + quad * 8]);
        #pragma unroll
        for (int i = 0; i < 4; i++)
            #pragma unroll
            for (int j = 0; j < 4; j++)
                acc[i][j] = __builtin_amdgcn_mfma_f32_16x16x32_bf16(af[i], bf[j], acc[i][j], 0, 0, 0);
    }

    #pragma unroll
    for (int i = 0; i < 4; i++) {
        #pragma unroll
        for (int j = 0; j < 4; j++) {
            #pragma unroll
            for (int r = 0; r < 4; r++) {
                int m = m0 + wm + i * 16 + quad * 4 + r;
                int n = n0 + wn + j * 16 + l16;
                if (EPI == 0) {
                    ushort v = f2bf(acc[i][j][r]);
                    int b = m >> 11, t = m & 2047;
                    int part = n >> 10, c = n & 1023;
                    int head = c >> 6, off = c & 63;
                    if (part == 0)      ((ushort*)O0)[(((size_t)(b * NH + head)) * T_SEQ + t) * HD + off] = v;
                    else if (part == 1) O1[(((size_t)(b * NH + head)) * T_SEQ + t) * HD + off] = v;
                    else                O2[(((size_t)(b * NH + head)) * HD + off) * T_SEQ + t] = v;
                } else {
                    ((float*)O0)[(size_t)m * N + n] = acc[i][j][r];
                }
            }
        }
    }
}

// ---------------- flash attention, one block = (b,h, 64-row q tile) ----------
__global__ __launch_bounds__(256, 2)
void attn_kernel(const ushort* __restrict__ Q, const ushort* __restrict__ Kk,
                 const ushort* __restrict__ Vt, ushort* __restrict__ Oout) {
    __shared__ __align__(16) ushort P[4][16 * 72];   // per-wave P tile, pad 64->72
    const int tid  = threadIdx.x;
    const int wave = tid >> 6, lane = tid & 63;
    const int quad = lane >> 4, l16 = lane & 15;
    const int qt = blockIdx.x & 31;       // T/64 = 32 q tiles
    const int bh = blockIdx.x >> 5;       // 0..31
    const int b = bh >> 4, h = bh & 15;

    const ushort* qp = Q  + (size_t)bh * T_SEQ * HD;
    const ushort* kp = Kk + (size_t)bh * T_SEQ * HD;
    const ushort* vp = Vt + (size_t)bh * HD * T_SEQ;

    const int qr0 = qt * 64 + wave * 16;  // this wave's 16 q rows
    short8 qf[2];
    #pragma unroll
    for (int kb = 0; kb < 2; kb++)
        qf[kb] = *(const short8*)(qp + (size_t)(qr0 + l16) * HD + kb * 32 + quad * 8);

    floatx4 o[4];
    #pragma unroll
    for (int nb = 0; nb < 4; nb++) o[nb] = (floatx4){0.f, 0.f, 0.f, 0.f};
    float mst[4], lst[4];
    #pragma unroll
    for (int r = 0; r < 4; r++) { mst[r] = -1e30f; lst[r] = 0.f; }

    ushort* pw = &P[wave][0];
    const float scale = 0.125f;  // 1/sqrt(64)

    for (int kt = 0; kt <= qt; kt++) {
        floatx4 s[4];
        #pragma unroll
        for (int j = 0; j < 4; j++) s[j] = (floatx4){0.f, 0.f, 0.f, 0.f};
        #pragma unroll
        for (int kb = 0; kb < 2; kb++)
            #pragma unroll
            for (int j = 0; j < 4; j++) {
                short8 kf = *(const short8*)(kp + (size_t)(kt * 64 + j * 16 + l16) * HD + kb * 32 + quad * 8);
                s[j] = __builtin_amdgcn_mfma_f32_16x16x32_bf16(qf[kb], kf, s[j], 0, 0, 0);
            }

        if (kt == qt) {   // diagonal tile: causal mask
            #pragma unroll
            for (int j = 0; j < 4; j++)
                #pragma unroll
                for (int r = 0; r < 4; r++) {
                    int key  = kt * 64 + j * 16 + l16;
                    int qrow = qr0 + quad * 4 + r;
                    float v = s[j][r] * scale;
                    s[j][r] = (key > qrow) ? -1e30f : v;
                }
        } else {
            #pragma unroll
            for (int j = 0; j < 4; j++)
                #pragma unroll
                for (int r = 0; r < 4; r++) s[j][r] *= scale;
        }

        float mnew[4], alpha[4];
        #pragma unroll
        for (int r = 0; r < 4; r++) {
            float t = fmaxf(fmaxf(s[0][r], s[1][r]), fmaxf(s[2][r], s[3][r]));
            t = fmaxf(t, __shfl_xor(t, 1));
            t = fmaxf(t, __shfl_xor(t, 2));
            t = fmaxf(t, __shfl_xor(t, 4));
            t = fmaxf(t, __shfl_xor(t, 8));
            mnew[r]  = fmaxf(mst[r], t);
            alpha[r] = __expf(mst[r] - mnew[r]);
            mst[r]   = mnew[r];
        }
        #pragma unroll
        for (int r = 0; r < 4; r++) {
            float acc = 0.f;
            #pragma unroll
            for (int j = 0; j < 4; j++) {
                float p = __expf(s[j][r] - mnew[r]);
                s[j][r] = p;
                acc += p;
            }
            acc += __shfl_xor(acc, 1);
            acc += __shfl_xor(acc, 2);
            acc += __shfl_xor(acc, 4);
            acc += __shfl_xor(acc, 8);
            lst[r] = lst[r] * alpha[r] + acc;
            o[0][r] *= alpha[r]; o[1][r] *= alpha[r];
            o[2][r] *= alpha[r]; o[3][r] *= alpha[r];
        }

        // P (C-layout) -> LDS -> A-operand layout
        __syncthreads();
        #pragma unroll
        for (int j = 0; j < 4; j++)
            #pragma unroll
            for (int r = 0; r < 4; r++)
                pw[(quad * 4 + r) * 72 + j * 16 + l16] = f2bf(s[j][r]);
        __syncthreads();
        short8 pf[2];
        pf[0] = *(const short8*)(pw + l16 * 72 + quad * 8);
        pf[1] = *(const short8*)(pw + l16 * 72 + 32 + quad * 8);
        #pragma unroll
        for (int kb = 0; kb < 2; kb++)
            #pragma unroll
            for (int nb = 0; nb < 4; nb++) {
                short8 vf = *(const short8*)(vp + (size_t)(nb * 16 + l16) * T_SEQ + kt * 64 + kb * 32 + quad * 8);
                o[nb] = __builtin_amdgcn_mfma_f32_16x16x32_bf16(pf[kb], vf, o[nb], 0, 0, 0);
            }
    }

    #pragma unroll
    for (int nb = 0; nb < 4; nb++)
        #pragma unroll
        for (int r = 0; r < 4; r++) {
            int t = qt * 64 + wave * 16 + quad * 4 + r;
            float val = o[nb][r] / lst[r];
            Oout[(((size_t)b * T_SEQ + t) * NH + h) * HD + nb * 16 + l16] = f2bf(val);
        }
}

extern "C" void kernel_launch(void* const* d_in, const int* in_sizes, int n_in,
                              void* d_out, int out_size, void* d_ws, size_t ws_size,
                              hipStream_t stream) {
    const float* x    = (const float*)d_in[0];   // [2,2048,1024] fp32
    const float* Wqkv = (const float*)d_in[1];   // [1024,3072]  fp32
    const float* Wout = (const float*)d_in[2];   // [1024,1024]  fp32
    ushort* ws = (ushort*)d_ws;

    ushort* wt_qkv = ws;                               // bf16 [3072][1024]
    ushort* wt_out = wt_qkv + 3072 * 1024;             // bf16 [1024][1024]
    ushort* q_ws   = wt_out + 1024 * 1024;             // bf16 [B,H,T,hd] = 4194304
    ushort* k_ws   = q_ws + 4194304;
    ushort* v_t    = k_ws + 4194304;                   // bf16 [B,H,hd,T]
    ushort* a_out  = v_t + 4194304;                    // bf16 [B,T,C]

    transpose_f32_bf16<<<dim3(96, 32), 256, 0, stream>>>(Wqkv, wt_qkv, 1024, 3072);
    transpose_f32_bf16<<<dim3(32, 32), 256, 0, stream>>>(Wout, wt_out, 1024, 1024);

    // qkv projection (A fp32 -> bf16 in staging) + scatter to per-head layouts
    gemm_bt<0><<<dim3(32, 24), 256, 0, stream>>>(x, wt_qkv, q_ws, k_ws, v_t, 4096, 3072, 1024);

    // attention: 2*16*32 = 1024 blocks
    attn_kernel<<<dim3(1024), 256, 0, stream>>>(q_ws, k_ws, v_t, a_out);

    // output projection (A bf16, output fp32)
    gemm_bt<1><<<dim3(32, 8), 256, 0, stream>>>(a_out, wt_out, (float*)d_out, nullptr, nullptr,
                                                4096, 1024, 1024);
}

// Round 3
// 244.747 us; speedup vs baseline: 1.5330x; 1.5330x over previous
//
#include <hip/hip_runtime.h>

typedef __attribute__((ext_vector_type(8))) short short8;
typedef __attribute__((ext_vector_type(4))) float floatx4;

#define T_SEQ 2048
#define NH    16
#define HD    64

__device__ __forceinline__ ushort f2bf(float f) {
    union { float f; unsigned u; } un; un.f = f;
    unsigned r = un.u + 0x7fff + ((un.u >> 16) & 1);
    return (ushort)(r >> 16);
}

typedef const __attribute__((address_space(1))) unsigned int* gp1_t;
typedef __attribute__((address_space(3))) unsigned int* lp3_t;
__device__ __forceinline__ void gl_lds16(const ushort* g, ushort* l) {
    __builtin_amdgcn_global_load_lds((gp1_t)g, (lp3_t)l, 16, 0, 0);
}

// -------- transpose + convert: in fp32 [R][C] -> out bf16 [C][R] ----------
__global__ void transpose_f32_bf16(const float* __restrict__ in, ushort* __restrict__ out,
                                   int R, int C) {
    __shared__ ushort tile[32][33];
    const int tx = threadIdx.x & 31, ty = threadIdx.x >> 5;
    const int bx = blockIdx.x * 32;
    const int by = blockIdx.y * 32;
    #pragma unroll
    for (int i = ty; i < 32; i += 8)
        tile[i][tx] = f2bf(in[(size_t)(by + i) * C + bx + tx]);
    __syncthreads();
    #pragma unroll
    for (int i = ty; i < 32; i += 8)
        out[(size_t)(bx + i) * R + by + tx] = tile[tx][i];
}

// -------- elementwise fp32 -> bf16 ----------
__global__ void convert_f32_bf16(const float* __restrict__ in, ushort* __restrict__ out) {
    size_t i = ((size_t)blockIdx.x * 256 + threadIdx.x) * 8;
    float4 f0 = *(const float4*)(in + i);
    float4 f1 = *(const float4*)(in + i + 4);
    short8 v;
    v[0] = (short)f2bf(f0.x); v[1] = (short)f2bf(f0.y);
    v[2] = (short)f2bf(f0.z); v[3] = (short)f2bf(f0.w);
    v[4] = (short)f2bf(f1.x); v[5] = (short)f2bf(f1.y);
    v[6] = (short)f2bf(f1.z); v[7] = (short)f2bf(f1.w);
    *(short8*)(out + i) = v;
}

// ---------------- GEMM: C[M][N] = A[M][K] * Bt[N][K]^T  (bf16 MFMA, fp32 acc) --
// m97 structure: global_load_lds width-16 staging, 128x128 tile, BK=32.
// 16B-chunk XOR swizzle on the K dimension kills ds_read bank conflicts.
// EPI==0: scatter bf16 into q[B,H,T,hd], k[B,H,T,hd], vT[B,H,hd,T] (N==3072)
// EPI==1: fp32 row-major [M][N] into O0
template <int EPI>
__global__ __launch_bounds__(256, 2)
void gemm_bt(const ushort* __restrict__ A, const ushort* __restrict__ Bt,
             void* __restrict__ O0, ushort* __restrict__ O1, ushort* __restrict__ O2,
             int M, int N, int K) {
    __shared__ __align__(16) ushort As[128 * 32];
    __shared__ __align__(16) ushort Bs[128 * 32];
    const int tid  = threadIdx.x;
    const int wave = tid >> 6, lane = tid & 63;
    const int quad = lane >> 4, l16 = lane & 15;
    const int wm = (wave >> 1) * 64, wn = (wave & 1) * 64;
    const int m0 = blockIdx.x * 128, n0 = blockIdx.y * 128;

    // staging: 512 chunks of 16B per operand; thread covers chunks tid, tid+256.
    // LDS chunk c holds global K-chunk ((c&3) ^ ((row>>1)&3)) of row c>>2.
    const int c0 = tid, c1 = tid + 256;
    const int row0 = c0 >> 2, row1 = c1 >> 2;
    const int g0 = (((c0 & 3) ^ ((row0 >> 1) & 3))) * 8;
    const int g1 = (((c1 & 3) ^ ((row1 >> 1) & 3))) * 8;
    const ushort* aP0 = A  + (size_t)(m0 + row0) * K + g0;
    const ushort* aP1 = A  + (size_t)(m0 + row1) * K + g1;
    const ushort* bP0 = Bt + (size_t)(n0 + row0) * K + g0;
    const ushort* bP1 = Bt + (size_t)(n0 + row1) * K + g1;

    floatx4 acc[4][4];
    #pragma unroll
    for (int i = 0; i < 4; i++)
        #pragma unroll
        for (int j = 0; j < 4; j++)
            acc[i][j] = (floatx4){0.f, 0.f, 0.f, 0.f};

    const int col_sw = (quad ^ ((l16 >> 1) & 3)) * 8;   // swizzled K-chunk for frag reads

    for (int k0 = 0; k0 < K; k0 += 32) {
        __syncthreads();
        gl_lds16(aP0 + k0, &As[c0 * 8]);
        gl_lds16(aP1 + k0, &As[c1 * 8]);
        gl_lds16(bP0 + k0, &Bs[c0 * 8]);
        gl_lds16(bP1 + k0, &Bs[c1 * 8]);
        __syncthreads();
        short8 af[4], bf[4];
        #pragma unroll
        for (int i = 0; i < 4; i++)
            af[i] = *(const short8*)(&As[(wm + i * 16 + l16) * 32 + col_sw]);
        #pragma unroll
        for (int j = 0; j < 4; j++)
            bf[j] = *(const short8*)(&Bs[(wn + j * 16 + l16) * 32 + col_sw]);
        #pragma unroll
        for (int i = 0; i < 4; i++)
            #pragma unroll
            for (int j = 0; j < 4; j++)
                acc[i][j] = __builtin_amdgcn_mfma_f32_16x16x32_bf16(af[i], bf[j], acc[i][j], 0, 0, 0);
    }

    #pragma unroll
    for (int i = 0; i < 4; i++) {
        #pragma unroll
        for (int j = 0; j < 4; j++) {
            #pragma unroll
            for (int r = 0; r < 4; r++) {
                int m = m0 + wm + i * 16 + quad * 4 + r;
                int n = n0 + wn + j * 16 + l16;
                if (EPI == 0) {
                    ushort v = f2bf(acc[i][j][r]);
                    int b = m >> 11, t = m & 2047;
                    int part = n >> 10, c = n & 1023;
                    int head = c >> 6, off = c & 63;
                    if (part == 0)      ((ushort*)O0)[(((size_t)(b * NH + head)) * T_SEQ + t) * HD + off] = v;
                    else if (part == 1) O1[(((size_t)(b * NH + head)) * T_SEQ + t) * HD + off] = v;
                    else                O2[(((size_t)(b * NH + head)) * HD + off) * T_SEQ + t] = v;
                } else {
                    ((float*)O0)[(size_t)m * N + n] = acc[i][j][r];
                }
            }
        }
    }
}

// ---------------- flash attention: block = (b,h, 128-row q tile) -------------
// 4 waves; wave w owns q rows [w*32, w*32+32) as two 16-row MFMA tiles.
// K/V (64 keys x 64 dims) staged once per block in double-buffered LDS;
// next tile prefetched into registers before compute of current tile.
__global__ __launch_bounds__(256, 2)
void attn_kernel(const ushort* __restrict__ Q, const ushort* __restrict__ Kk,
                 const ushort* __restrict__ Vt, ushort* __restrict__ Oout) {
    __shared__ __align__(16) ushort Ks[2][64 * 72];
    __shared__ __align__(16) ushort Vs[2][64 * 72];
    __shared__ __align__(16) ushort P[4][32 * 72];
    const int tid  = threadIdx.x;
    const int wave = tid >> 6, lane = tid & 63;
    const int quad = lane >> 4, l16 = lane & 15;
    const int idx = blockIdx.x;
    const int qb = 15 - (idx >> 5);    // heavy q-tiles dispatched first
    const int bh = idx & 31;
    const int b = bh >> 4, h = bh & 15;

    const ushort* qp = Q  + (size_t)bh * T_SEQ * HD;
    const ushort* kp = Kk + (size_t)bh * T_SEQ * HD;
    const ushort* vp = Vt + (size_t)bh * HD * T_SEQ;

    const int q0w = qb * 128 + wave * 32;

    short8 qf[2][2];
    #pragma unroll
    for (int qi = 0; qi < 2; qi++)
        #pragma unroll
        for (int kb = 0; kb < 2; kb++)
            qf[qi][kb] = *(const short8*)(qp + (size_t)(q0w + qi * 16 + l16) * HD + kb * 32 + quad * 8);

    floatx4 o[2][4];
    float mst[2][4], lst[2][4];
    #pragma unroll
    for (int qi = 0; qi < 2; qi++)
        #pragma unroll
        for (int r = 0; r < 4; r++) {
            o[qi][r >> 2] = o[qi][r >> 2];  // no-op to appease unroll
        }
    #pragma unroll
    for (int qi = 0; qi < 2; qi++) {
        #pragma unroll
        for (int nb = 0; nb < 4; nb++) o[qi][nb] = (floatx4){0.f, 0.f, 0.f, 0.f};
        #pragma unroll
        for (int r = 0; r < 4; r++) { mst[qi][r] = -1e30f; lst[qi][r] = 0.f; }
    }

    // staging geometry: 512 chunks of 16B per operand; thread covers tid, tid+256
    const int c0 = tid, c1 = tid + 256;
    const int kr0 = c0 >> 3, kc0 = (c0 & 7) * 8;
    const int kr1 = c1 >> 3, kc1 = (c1 & 7) * 8;
    const size_t koff0 = (size_t)kr0 * HD + kc0,   koff1 = (size_t)kr1 * HD + kc1;
    const size_t voff0 = (size_t)kr0 * T_SEQ + kc0, voff1 = (size_t)kr1 * T_SEQ + kc1;
    const int l0 = kr0 * 72 + kc0, l1 = kr1 * 72 + kc1;

    uint4 kg0, kg1, vg0, vg1;
    kg0 = *(const uint4*)(kp + koff0);
    kg1 = *(const uint4*)(kp + koff1);
    vg0 = *(const uint4*)(vp + voff0);
    vg1 = *(const uint4*)(vp + voff1);
    *(uint4*)(&Ks[0][l0]) = kg0; *(uint4*)(&Ks[0][l1]) = kg1;
    *(uint4*)(&Vs[0][l0]) = vg0; *(uint4*)(&Vs[0][l1]) = vg1;
    __syncthreads();

    const int n_kt = 2 * qb + 2;
    const float scale2 = 0.125f * 1.44269504088896f;   // exp2 domain
    ushort* pw = &P[wave][0];

    for (int kt = 0; kt < n_kt; ++kt) {
        const int buf = kt & 1;
        const bool have_next = (kt + 1 < n_kt);
        if (have_next) {   // prefetch next tile into registers (latency hidden by compute)
            kg0 = *(const uint4*)(kp + (size_t)(kt + 1) * 64 * HD + koff0);
            kg1 = *(const uint4*)(kp + (size_t)(kt + 1) * 64 * HD + koff1);
            vg0 = *(const uint4*)(vp + (kt + 1) * 64 + voff0);
            vg1 = *(const uint4*)(vp + (kt + 1) * 64 + voff1);
        }

        if (kt * 64 <= q0w + 31) {    // wave has unmasked work in this tile
            floatx4 s[2][4];
            #pragma unroll
            for (int qi = 0; qi < 2; qi++)
                #pragma unroll
                for (int j = 0; j < 4; j++) s[qi][j] = (floatx4){0.f, 0.f, 0.f, 0.f};
            #pragma unroll
            for (int kb = 0; kb < 2; kb++)
                #pragma unroll
                for (int j = 0; j < 4; j++) {
                    short8 kf = *(const short8*)(&Ks[buf][(j * 16 + l16) * 72 + kb * 32 + quad * 8]);
                    #pragma unroll
                    for (int qi = 0; qi < 2; qi++)
                        s[qi][j] = __builtin_amdgcn_mfma_f32_16x16x32_bf16(qf[qi][kb], kf, s[qi][j], 0, 0, 0);
                }

            if (kt * 64 + 63 > q0w) {   // tile touches the diagonal for this wave
                #pragma unroll
                for (int qi = 0; qi < 2; qi++)
                    #pragma unroll
                    for (int j = 0; j < 4; j++)
                        #pragma unroll
                        for (int r = 0; r < 4; r++) {
                            int key = kt * 64 + j * 16 + l16;
                            int row = q0w + qi * 16 + quad * 4 + r;
                            float v = s[qi][j][r] * scale2;
                            s[qi][j][r] = (key > row) ? -1e30f : v;
                        }
            } else {
                #pragma unroll
                for (int qi = 0; qi < 2; qi++)
                    #pragma unroll
                    for (int j = 0; j < 4; j++)
                        #pragma unroll
                        for (int r = 0; r < 4; r++) s[qi][j][r] *= scale2;
            }

            #pragma unroll
            for (int qi = 0; qi < 2; qi++)
                #pragma unroll
                for (int r = 0; r < 4; r++) {
                    float t = fmaxf(fmaxf(s[qi][0][r], s[qi][1][r]), fmaxf(s[qi][2][r], s[qi][3][r]));
                    t = fmaxf(t, __shfl_xor(t, 1));
                    t = fmaxf(t, __shfl_xor(t, 2));
                    t = fmaxf(t, __shfl_xor(t, 4));
                    t = fmaxf(t, __shfl_xor(t, 8));
                    float mnew  = fmaxf(mst[qi][r], t);
                    float alpha = exp2f(mst[qi][r] - mnew);
                    mst[qi][r]  = mnew;
                    float acc = 0.f;
                    #pragma unroll
                    for (int j = 0; j < 4; j++) {
                        float p = exp2f(s[qi][j][r] - mnew);
                        s[qi][j][r] = p;
                        acc += p;
                    }
                    acc += __shfl_xor(acc, 1);
                    acc += __shfl_xor(acc, 2);
                    acc += __shfl_xor(acc, 4);
                    acc += __shfl_xor(acc, 8);
                    lst[qi][r] = lst[qi][r] * alpha + acc;
                    #pragma unroll
                    for (int nb = 0; nb < 4; nb++) o[qi][nb][r] *= alpha;
                }

            // P (C-layout) -> per-wave LDS -> A-operand layout (no block barrier needed)
            #pragma unroll
            for (int qi = 0; qi < 2; qi++)
                #pragma unroll
                for (int j = 0; j < 4; j++)
                    #pragma unroll
                    for (int r = 0; r < 4; r++)
                        pw[(qi * 16 + quad * 4 + r) * 72 + j * 16 + l16] = f2bf(s[qi][j][r]);
            short8 pf[2][2];
            #pragma unroll
            for (int qi = 0; qi < 2; qi++) {
                pf[qi][0] = *(const short8*)(pw + (qi * 16 + l16) * 72 + quad * 8);
                pf[qi][1] = *(const short8*)(pw + (qi * 16 + l16) * 72 + 32 + quad * 8);
            }
            #pragma unroll
            for (int kb = 0; kb < 2; kb++)
                #pragma unroll
                for (int nb = 0; nb < 4; nb++) {
                    short8 vf = *(const short8*)(&Vs[buf][(nb * 16 + l16) * 72 + kb * 32 + quad * 8]);
                    #pragma unroll
                    for (int qi = 0; qi < 2; qi++)
                        o[qi][nb] = __builtin_amdgcn_mfma_f32_16x16x32_bf16(pf[qi][kb], vf, o[qi][nb], 0, 0, 0);
                }
        }

        if (have_next) {
            __syncthreads();   // all waves done reading buf[(kt+1)&1] (used in kt-1)
            const int nbuf = (kt + 1) & 1;
            *(uint4*)(&Ks[nbuf][l0]) = kg0; *(uint4*)(&Ks[nbuf][l1]) = kg1;
            *(uint4*)(&Vs[nbuf][l0]) = vg0; *(uint4*)(&Vs[nbuf][l1]) = vg1;
            __syncthreads();   // staged data visible before next tile's reads
        }
    }

    #pragma unroll
    for (int qi = 0; qi < 2; qi++)
        #pragma unroll
        for (int nb = 0; nb < 4; nb++)
            #pragma unroll
            for (int r = 0; r < 4; r++) {
                int t = qb * 128 + wave * 32 + qi * 16 + quad * 4 + r;
                float val = o[qi][nb][r] / lst[qi][r];
                Oout[(((size_t)b * T_SEQ + t) * NH + h) * HD + nb * 16 + l16] = f2bf(val);
            }
}

extern "C" void kernel_launch(void* const* d_in, const int* in_sizes, int n_in,
                              void* d_out, int out_size, void* d_ws, size_t ws_size,
                              hipStream_t stream) {
    const float* x    = (const float*)d_in[0];   // [2,2048,1024] fp32
    const float* Wqkv = (const float*)d_in[1];   // [1024,3072]  fp32
    const float* Wout = (const float*)d_in[2];   // [1024,1024]  fp32
    ushort* ws = (ushort*)d_ws;

    ushort* wt_qkv = ws;                               // bf16 [3072][1024]
    ushort* wt_out = wt_qkv + 3072 * 1024;             // bf16 [1024][1024]
    ushort* q_ws   = wt_out + 1024 * 1024;             // bf16 [B,H,T,hd]
    ushort* k_ws   = q_ws + 4194304;
    ushort* v_t    = k_ws + 4194304;                   // bf16 [B,H,hd,T]
    ushort* a_out  = v_t + 4194304;                    // bf16 [B,T,C]
    ushort* x_bf   = a_out + 4194304;                  // bf16 [B,T,C]

    transpose_f32_bf16<<<dim3(96, 32), 256, 0, stream>>>(Wqkv, wt_qkv, 1024, 3072);
    transpose_f32_bf16<<<dim3(32, 32), 256, 0, stream>>>(Wout, wt_out, 1024, 1024);
    convert_f32_bf16<<<dim3(2048), 256, 0, stream>>>(x, x_bf);

    gemm_bt<0><<<dim3(32, 24), 256, 0, stream>>>(x_bf, wt_qkv, q_ws, k_ws, v_t, 4096, 3072, 1024);

    attn_kernel<<<dim3(512), 256, 0, stream>>>(q_ws, k_ws, v_t, a_out);

    gemm_bt<1><<<dim3(32, 8), 256, 0, stream>>>(a_out, wt_out, (float*)d_out, nullptr, nullptr,
                                                4096, 1024, 1024);
}